// Round 1
// baseline (1225.861 us; speedup 1.0000x reference)
//
#include <hip/hip_runtime.h>
#include <math.h>

#define BB 16
#define SS 4096
#define HH 1024
#define RT 16     // rows per scores-block
#define SCH 256   // s-chunk for weighted-sum kernel

// d_ws layout:
//   [0, 4 MB)            : Wt[k][o] = W[o][k]  (1024x1024 fp32)
//   [4 MB, 4 MB + 256 KB): scores / attn probs, B*S fp32

// ---------------- W transpose (runs once per launch, ~8 MB traffic) --------
__global__ __launch_bounds__(256) void transpose_W(const float* __restrict__ W,
                                                   float* __restrict__ Wt) {
  __shared__ float t[32][33];            // +1 pad: conflict-free transpose
  int k0 = blockIdx.x * 32, o0 = blockIdx.y * 32;
  int tx = threadIdx.x, ty = threadIdx.y;      // block (32,8)
#pragma unroll
  for (int i = 0; i < 32; i += 8)
    t[ty + i][tx] = W[(size_t)(o0 + ty + i) * HH + (k0 + tx)];
  __syncthreads();
#pragma unroll
  for (int i = 0; i < 32; i += 8)
    Wt[(size_t)(k0 + ty + i) * HH + (o0 + tx)] = t[tx][ty + i];
}

// ---------------- scores: tanh(x @ W^T + b) . key for valid rows -----------
// grid (SS/RT, BB), block 256.  Thread tile: 8 rows x 8 outputs.
// x-tile (16 rows x 1024 k) staged once in LDS transposed [k][row];
// per-k x reads are wave-uniform broadcast b128s. W streamed from global,
// coalesced (thread t owns o = (t&127)*4 + {0..3} and +512).
__global__ __launch_bounds__(256, 2) void scores_kernel(
    const float* __restrict__ x, const int* __restrict__ lengths,
    const float* __restrict__ Wt, const float* __restrict__ bias,
    const float* __restrict__ key, float* __restrict__ scores) {
  int b = blockIdx.y;
  int s0 = blockIdx.x * RT;
  int L = lengths[b];
  if (s0 >= L) return;                    // attn weight is 0 past L: skip

  __shared__ float xT[HH * RT];           // 64 KB: [k][row]
  __shared__ float red[4][8];             // per-wave row partials

  int tid = threadIdx.x;
  const float* xb = x + ((size_t)b * SS + s0) * HH;

  // stage x tile, coalesced global reads (consecutive tid -> consecutive k)
#pragma unroll
  for (int it = 0; it < (HH * RT) / 256; ++it) {
    int flat = it * 256 + tid;
    int row = flat >> 10;                 // /HH
    int k = flat & (HH - 1);
    xT[k * RT + row] = xb[(size_t)row * HH + k];
  }
  __syncthreads();

  int og = tid & 127;                     // 128 o-groups of (4 + 4) outputs
  int rg = tid >> 7;                      // 2 row-groups of 8 rows
  const float* w0 = Wt + og * 4;          // o = og*4 + c
  const float* w1 = Wt + og * 4 + 512;    // o = 512 + og*4 + c
  const float* xrow = xT + rg * 8;

  float acc[8][8];
#pragma unroll
  for (int r = 0; r < 8; ++r)
#pragma unroll
    for (int c = 0; c < 8; ++c) acc[r][c] = 0.f;

#pragma unroll 2
  for (int k = 0; k < HH; ++k) {
    float4 wa = *(const float4*)(w0 + (size_t)k * HH);   // coalesced, L2/L3-hot
    float4 wb = *(const float4*)(w1 + (size_t)k * HH);
    float4 xa = *(const float4*)(xrow + k * RT);         // broadcast ds_read_b128
    float4 xc = *(const float4*)(xrow + k * RT + 4);
    float xs[8] = {xa.x, xa.y, xa.z, xa.w, xc.x, xc.y, xc.z, xc.w};
    float ws[8] = {wa.x, wa.y, wa.z, wa.w, wb.x, wb.y, wb.z, wb.w};
#pragma unroll
    for (int r = 0; r < 8; ++r)
#pragma unroll
      for (int c = 0; c < 8; ++c)
        acc[r][c] = fmaf(xs[r], ws[c], acc[r][c]);       // 64 v_fmac_f32 / k
  }

  // epilogue: tanh(pre + b[o]) * key[o], summed over this thread's 8 o's
  float bv[8], kv[8];
#pragma unroll
  for (int c = 0; c < 8; ++c) {
    int o = og * 4 + (c & 3) + (c >> 2) * 512;
    bv[c] = bias[o];
    kv[c] = key[o];
  }
  float sc[8];
#pragma unroll
  for (int r = 0; r < 8; ++r) {
    float s = 0.f;
#pragma unroll
    for (int c = 0; c < 8; ++c) s += tanhf(acc[r][c] + bv[c]) * kv[c];
    sc[r] = s;
  }

  // reduce over o-groups: wave shuffle, then combine the 2 waves per row-group
  int wave = tid >> 6;
#pragma unroll
  for (int r = 0; r < 8; ++r) {
    float v = sc[r];
    for (int off = 32; off > 0; off >>= 1) v += __shfl_down(v, off);
    if ((tid & 63) == 0) red[wave][r] = v;
  }
  __syncthreads();
  if (tid < RT) {
    int row = tid;
    float v = (row < 8) ? (red[0][row] + red[1][row])
                        : (red[2][row - 8] + red[3][row - 8]);
    scores[(size_t)b * SS + s0 + row] = v;
  }
}

// ---------------- masked softmax over s < L, in place ----------------------
__global__ __launch_bounds__(256) void softmax_kernel(float* __restrict__ sc,
                                                      const int* __restrict__ lengths) {
  int b = blockIdx.x;
  int L = lengths[b];
  float* p = sc + (size_t)b * SS;
  __shared__ float sred[34];
  int tid = threadIdx.x;

  float m = -3.0e38f;
  for (int s = tid; s < L; s += 256) m = fmaxf(m, p[s]);
  for (int off = 32; off > 0; off >>= 1) m = fmaxf(m, __shfl_down(m, off));
  if ((tid & 63) == 0) sred[tid >> 6] = m;
  __syncthreads();
  if (tid == 0) {
    float mm = sred[0];
    for (int w = 1; w < 4; ++w) mm = fmaxf(mm, sred[w]);
    sred[32] = mm;
  }
  __syncthreads();
  m = sred[32];

  float z = 0.f;
  for (int s = tid; s < L; s += 256) z += expf(p[s] - m);
  for (int off = 32; off > 0; off >>= 1) z += __shfl_down(z, off);
  if ((tid & 63) == 0) sred[tid >> 6] = z;
  __syncthreads();
  if (tid == 0) {
    float zz = 0.f;
    for (int w = 0; w < 4; ++w) zz += sred[w];
    sred[33] = zz;
  }
  __syncthreads();
  float inv = 1.f / sred[33];
  for (int s = tid; s < L; s += 256) p[s] = expf(p[s] - m) * inv;
}

// ---------------- out[b,h] = sum_{s<L} p[b,s] * x[b,s,h] -------------------
// grid (SS/SCH, BB), block 256, thread owns 4 h's (float4), atomic combine.
__global__ __launch_bounds__(256) void wsum_kernel(const float* __restrict__ x,
                                                   const float* __restrict__ p,
                                                   const int* __restrict__ lengths,
                                                   float* __restrict__ out) {
  int b = blockIdx.y;
  int L = lengths[b];
  int sbeg = blockIdx.x * SCH;
  if (sbeg >= L) return;
  int send = min(sbeg + SCH, L);
  int h = threadIdx.x * 4;
  const float* xb = x + (size_t)b * SS * HH;
  const float* pb = p + (size_t)b * SS;
  float4 acc = {0.f, 0.f, 0.f, 0.f};
  for (int s = sbeg; s < send; ++s) {
    float w = pb[s];
    float4 v = *(const float4*)(xb + (size_t)s * HH + h);
    acc.x = fmaf(w, v.x, acc.x);
    acc.y = fmaf(w, v.y, acc.y);
    acc.z = fmaf(w, v.z, acc.z);
    acc.w = fmaf(w, v.w, acc.w);
  }
  float* o = out + (size_t)b * HH + h;
  atomicAdd(o + 0, acc.x);
  atomicAdd(o + 1, acc.y);
  atomicAdd(o + 2, acc.z);
  atomicAdd(o + 3, acc.w);
}

extern "C" void kernel_launch(void* const* d_in, const int* in_sizes, int n_in,
                              void* d_out, int out_size, void* d_ws, size_t ws_size,
                              hipStream_t stream) {
  const float* x = (const float*)d_in[0];
  const int* lengths = (const int*)d_in[1];
  const float* W = (const float*)d_in[2];
  const float* bias = (const float*)d_in[3];
  const float* key = (const float*)d_in[4];
  float* out = (float*)d_out;

  float* Wt = (float*)d_ws;                                  // 4 MB
  float* scores = (float*)((char*)d_ws + (size_t)HH * HH * 4); // 256 KB

  hipMemsetAsync(d_out, 0, (size_t)out_size * sizeof(float), stream);
  transpose_W<<<dim3(HH / 32, HH / 32), dim3(32, 8), 0, stream>>>(W, Wt);
  scores_kernel<<<dim3(SS / RT, BB), 256, 0, stream>>>(x, lengths, Wt, bias, key, scores);
  softmax_kernel<<<dim3(BB), 256, 0, stream>>>(scores, lengths);
  wsum_kernel<<<dim3(SS / SCH, BB), 256, 0, stream>>>(x, scores, lengths, out);
}

// Round 2
// 637.842 us; speedup vs baseline: 1.9219x; 1.9219x over previous
//
#include <hip/hip_runtime.h>
#include <math.h>

#define BB 16
#define SS 4096
#define HH 1024
#define SCH 64    // s-chunk for weighted-sum kernel

// d_ws layout:
//   [0, 4 MB)            : W tiled hi/lo bf16: [ct(8)][kc(32)] blocks of 16 KB
//                          each block: hi 8 KB = n(128) x k(32) bf16, then lo 8 KB
//   [4 MB, 4 MB + 256 KB): scores / attn probs, B*S fp32 (atomicAdd target)

typedef __attribute__((ext_vector_type(8))) short bf16x8;
typedef __attribute__((ext_vector_type(16))) float f32x16;

__device__ __forceinline__ void gl_lds16(const void* g, void* l) {
  __builtin_amdgcn_global_load_lds(
      (const __attribute__((address_space(1))) void*)g,
      (__attribute__((address_space(3))) void*)l, 16, 0, 0);
}

// ---- W -> tiled hi/lo bf16 (truncation split: hi = top16, lo = top16(res)) --
__global__ __launch_bounds__(256) void conv_w(const float* __restrict__ W,
                                              unsigned short* __restrict__ Bbuf) {
  int ct = blockIdx.x, kc = blockIdx.y;
  unsigned short* blk = Bbuf + (size_t)(ct * 32 + kc) * 8192;  // 16 KB / 2
  int tid = threadIdx.x;
#pragma unroll
  for (int it = 0; it < 16; ++it) {
    int flat = it * 256 + tid;
    int n = flat >> 5, kk = flat & 31;
    float f = W[(size_t)(ct * 128 + n) * HH + kc * 32 + kk];
    unsigned u = __float_as_uint(f);
    float hf = __uint_as_float(u & 0xffff0000u);
    blk[n * 32 + kk] = (unsigned short)(u >> 16);
    blk[4096 + n * 32 + kk] = (unsigned short)(__float_as_uint(f - hf) >> 16);
  }
}

// ---- scores GEMM: 3-stream split-bf16 MFMA, fused tanh.key epilogue --------
// grid (8 col-tiles, 512 row-tiles), block 256 (4 waves, 2x2 wave grid).
// LDS: As_hi[128][32] | As_lo | Bs_hi[128][32] | Bs_lo  (8 KB each, 32 KB).
__global__ __launch_bounds__(256, 2) void scores_gemm(
    const float* __restrict__ x, const int* __restrict__ lengths,
    const unsigned short* __restrict__ Bbuf, const float* __restrict__ bias,
    const float* __restrict__ key, float* __restrict__ scores) {
  int ct = blockIdx.x;
  int t = blockIdx.y;
  int b = t >> 5;
  int s0 = (t & 31) * 128;
  if (s0 >= lengths[b]) return;   // softmax/wsum never read s >= L

  __shared__ char lds[32768];
  int tid = threadIdx.x;
  int lane = tid & 63, w = tid >> 6;
  int wm = w & 1, wn = w >> 1;

  f32x16 acc[2][2];
#pragma unroll
  for (int mt = 0; mt < 2; ++mt)
#pragma unroll
    for (int nt = 0; nt < 2; ++nt)
#pragma unroll
      for (int i = 0; i < 16; ++i) acc[mt][nt][i] = 0.f;

  const float* xb = x + ((size_t)b * SS + s0) * HH;
  const char* Bblk0 = (const char*)Bbuf + (size_t)ct * 32 * 16384;

  int ar = tid >> 3;            // staging row 0..31 (+32*it)
  int ak = (tid & 7) * 4;       // staging k within 32

  int mrow = lane & 31;         // MFMA m (and n) index
  int khsel = lane >> 5;        // which 8-k half of a 16-k fragment
  char* aP = lds + (wm * 64 + mrow) * 64 + khsel * 16;
  char* bP = lds + 16384 + (wn * 64 + mrow) * 64 + khsel * 16;

  for (int kc = 0; kc < 32; ++kc) {
    // --- stage B (pre-tiled hi/lo bf16): 16 KB contiguous via global_load_lds
    const char* Bblk = Bblk0 + kc * 16384;
#pragma unroll
    for (int i = 0; i < 4; ++i) {
      int c = w * 4 + i;
      gl_lds16(Bblk + c * 1024 + lane * 16, lds + 16384 + c * 1024);
    }
    // --- stage A: load fp32 x, split to bf16 hi/lo in-flight
#pragma unroll
    for (int it = 0; it < 4; ++it) {
      int r = ar + it * 32;
      float4 v = *(const float4*)(xb + (size_t)r * HH + kc * 32 + ak);
      unsigned u0 = __float_as_uint(v.x), u1 = __float_as_uint(v.y);
      unsigned u2 = __float_as_uint(v.z), u3 = __float_as_uint(v.w);
      float l0 = v.x - __uint_as_float(u0 & 0xffff0000u);
      float l1 = v.y - __uint_as_float(u1 & 0xffff0000u);
      float l2 = v.z - __uint_as_float(u2 & 0xffff0000u);
      float l3 = v.w - __uint_as_float(u3 & 0xffff0000u);
      uint2 hp, lp;
      hp.x = (u0 >> 16) | (u1 & 0xffff0000u);
      hp.y = (u2 >> 16) | (u3 & 0xffff0000u);
      lp.x = (__float_as_uint(l0) >> 16) | (__float_as_uint(l1) & 0xffff0000u);
      lp.y = (__float_as_uint(l2) >> 16) | (__float_as_uint(l3) & 0xffff0000u);
      *(uint2*)(lds + r * 64 + ak * 2) = hp;
      *(uint2*)(lds + 8192 + r * 64 + ak * 2) = lp;
    }
    __syncthreads();   // drains vmcnt (lds-DMA) + lgkmcnt (ds_write)

    // --- 3-stream MFMA: acc += ah*bh + ah*bl + al*bh
#pragma unroll
    for (int kh = 0; kh < 2; ++kh) {
      bf16x8 ah[2], al[2], bh[2], bl[2];
#pragma unroll
      for (int mt = 0; mt < 2; ++mt) {
        ah[mt] = *(bf16x8*)(aP + mt * 2048 + kh * 32);
        al[mt] = *(bf16x8*)(aP + 8192 + mt * 2048 + kh * 32);
        bh[mt] = *(bf16x8*)(bP + mt * 2048 + kh * 32);
        bl[mt] = *(bf16x8*)(bP + 8192 + mt * 2048 + kh * 32);
      }
#pragma unroll
      for (int mt = 0; mt < 2; ++mt)
#pragma unroll
        for (int nt = 0; nt < 2; ++nt) {
          acc[mt][nt] = __builtin_amdgcn_mfma_f32_32x32x16_bf16(
              ah[mt], bh[nt], acc[mt][nt], 0, 0, 0);
          acc[mt][nt] = __builtin_amdgcn_mfma_f32_32x32x16_bf16(
              ah[mt], bl[nt], acc[mt][nt], 0, 0, 0);
          acc[mt][nt] = __builtin_amdgcn_mfma_f32_32x32x16_bf16(
              al[mt], bh[nt], acc[mt][nt], 0, 0, 0);
        }
    }
    __syncthreads();   // protect LDS before next staging pass
  }

  // --- epilogue: score[row] += sum_o tanh(pre + bias[o]) * key[o]
  // C/D map (32x32): col = lane&31, row = (reg&3) + 8*(reg>>2) + 4*(lane>>5)
  int col = lane & 31;
  int rbase = (lane >> 5) * 4;
  float bo[2], ko[2];
#pragma unroll
  for (int nt = 0; nt < 2; ++nt) {
    int o = ct * 128 + wn * 64 + nt * 32 + col;
    bo[nt] = bias[o];
    ko[nt] = key[o];
  }
  float* srow = scores + (size_t)b * SS + s0;
#pragma unroll
  for (int mt = 0; mt < 2; ++mt) {
#pragma unroll
    for (int reg = 0; reg < 16; ++reg) {
      float sv = tanhf(acc[mt][0][reg] + bo[0]) * ko[0] +
                 tanhf(acc[mt][1][reg] + bo[1]) * ko[1];
#pragma unroll
      for (int off = 1; off < 32; off <<= 1) sv += __shfl_xor(sv, off);
      if (col == 0) {
        int row = wm * 64 + mt * 32 + (reg & 3) + 8 * (reg >> 2) + rbase;
        atomicAdd(srow + row, sv);
      }
    }
  }
}

// ---- masked softmax over s < L, in place -----------------------------------
__global__ __launch_bounds__(256) void softmax_kernel(float* __restrict__ sc,
                                                      const int* __restrict__ lengths) {
  int b = blockIdx.x;
  int L = lengths[b];
  float* p = sc + (size_t)b * SS;
  __shared__ float sred[34];
  int tid = threadIdx.x;

  float m = -3.0e38f;
  for (int s = tid; s < L; s += 256) m = fmaxf(m, p[s]);
  for (int off = 32; off > 0; off >>= 1) m = fmaxf(m, __shfl_down(m, off));
  if ((tid & 63) == 0) sred[tid >> 6] = m;
  __syncthreads();
  if (tid == 0) {
    float mm = sred[0];
    for (int w = 1; w < 4; ++w) mm = fmaxf(mm, sred[w]);
    sred[32] = mm;
  }
  __syncthreads();
  m = sred[32];

  float z = 0.f;
  for (int s = tid; s < L; s += 256) z += expf(p[s] - m);
  for (int off = 32; off > 0; off >>= 1) z += __shfl_down(z, off);
  if ((tid & 63) == 0) sred[tid >> 6] = z;
  __syncthreads();
  if (tid == 0) {
    float zz = 0.f;
    for (int w = 0; w < 4; ++w) zz += sred[w];
    sred[33] = zz;
  }
  __syncthreads();
  float inv = 1.f / sred[33];
  for (int s = tid; s < L; s += 256) p[s] = expf(p[s] - m) * inv;
}

// ---- out[b,h] = sum_{s<L} p[b,s] * x[b,s,h] --------------------------------
__global__ __launch_bounds__(256) void wsum_kernel(const float* __restrict__ x,
                                                   const float* __restrict__ p,
                                                   const int* __restrict__ lengths,
                                                   float* __restrict__ out) {
  int b = blockIdx.y;
  int L = lengths[b];
  int sbeg = blockIdx.x * SCH;
  if (sbeg >= L) return;
  int send = min(sbeg + SCH, L);
  int h = threadIdx.x * 4;
  const float* xb = x + (size_t)b * SS * HH;
  const float* pb = p + (size_t)b * SS;
  float4 acc = {0.f, 0.f, 0.f, 0.f};
  for (int s = sbeg; s < send; ++s) {
    float wgt = pb[s];
    float4 v = *(const float4*)(xb + (size_t)s * HH + h);
    acc.x = fmaf(wgt, v.x, acc.x);
    acc.y = fmaf(wgt, v.y, acc.y);
    acc.z = fmaf(wgt, v.z, acc.z);
    acc.w = fmaf(wgt, v.w, acc.w);
  }
  float* o = out + (size_t)b * HH + h;
  atomicAdd(o + 0, acc.x);
  atomicAdd(o + 1, acc.y);
  atomicAdd(o + 2, acc.z);
  atomicAdd(o + 3, acc.w);
}

extern "C" void kernel_launch(void* const* d_in, const int* in_sizes, int n_in,
                              void* d_out, int out_size, void* d_ws, size_t ws_size,
                              hipStream_t stream) {
  const float* x = (const float*)d_in[0];
  const int* lengths = (const int*)d_in[1];
  const float* W = (const float*)d_in[2];
  const float* bias = (const float*)d_in[3];
  const float* key = (const float*)d_in[4];
  float* out = (float*)d_out;

  unsigned short* Bbuf = (unsigned short*)d_ws;                   // 4 MB
  float* scores = (float*)((char*)d_ws + (size_t)4 * 1024 * 1024); // 256 KB

  hipMemsetAsync(d_out, 0, (size_t)out_size * sizeof(float), stream);
  hipMemsetAsync(scores, 0, (size_t)BB * SS * sizeof(float), stream);
  conv_w<<<dim3(8, 32), 256, 0, stream>>>(W, Bbuf);
  scores_gemm<<<dim3(8, 512), 256, 0, stream>>>(x, lengths, Bbuf, bias, key, scores);
  softmax_kernel<<<dim3(BB), 256, 0, stream>>>(scores, lengths);
  wsum_kernel<<<dim3(SS / SCH, BB), 256, 0, stream>>>(x, scores, lengths, out);
}